// Round 3
// baseline (564.127 us; speedup 1.0000x reference)
//
#include <hip/hip_runtime.h>
#include <hip/hip_bf16.h>
#include <cstdint>

typedef __attribute__((ext_vector_type(8))) short short8;     // 8 bf16 frag (4 VGPRs)
typedef __attribute__((ext_vector_type(16))) float f32x16;    // 32x32 accumulator
typedef unsigned short us;

#define BIN_SHIFT 9
#define BIN_NODES 512
#define CAPB 12288   // per-bin capacity (mean 8163, +45 sigma)
#define EPB 4096     // edges per binA block

__device__ __forceinline__ float bflo(uint32_t u) { return __builtin_bit_cast(float, u << 16); }
__device__ __forceinline__ float bfhi(uint32_t u) { return __builtin_bit_cast(float, u & 0xffff0000u); }

__device__ __forceinline__ us f32_to_bf16_rne(float f) {
  uint32_t u = __builtin_bit_cast(uint32_t, f);
  u += 0x7fffu + ((u >> 16) & 1u);
  return (us)(u >> 16);
}

// split f32 into truncated-bf16 hi + bf16 lo (residual); hi+lo ~= f to ~2^-16 rel
__device__ __forceinline__ void split2(float f, us& h, us& l) {
  uint32_t u = __builtin_bit_cast(uint32_t, f);
  h = (us)(u >> 16);
  float fh = __builtin_bit_cast(float, u & 0xffff0000u);
  float r = f - fh;  // exact
  l = (us)(__builtin_bit_cast(uint32_t, r) >> 16);
}

// ---------------- pass A: bin (dst,src) pairs by dst>>9 with dense batched appends ----------------
__global__ __launch_bounds__(256) void k_binA(
    const int* __restrict__ src, const int* __restrict__ dst,
    uint2* __restrict__ binbuf, int* __restrict__ gcur, int E, int nbins) {
  __shared__ uint2 stage[EPB];                       // 32 KB
  __shared__ int cnt[256], base[256], cur[256], gbase[256];
  int tid = threadIdx.x;
  int e0 = blockIdx.x * EPB;
  int ne = min(EPB, E - e0);
  if (ne <= 0) return;
  cnt[tid] = 0;
  __syncthreads();
  for (int i = tid; i < ne; i += 256) atomicAdd(&cnt[dst[e0 + i] >> BIN_SHIFT], 1);
  __syncthreads();
  // exclusive scan cnt[256] -> base (wave 0, 4 chunks of 64)
  if (tid < 64) {
    int carry = 0;
#pragma unroll
    for (int c = 0; c < 4; ++c) {
      int v = cnt[c * 64 + tid];
      int incl = v;
#pragma unroll
      for (int off = 1; off < 64; off <<= 1) {
        int t = __shfl_up(incl, off, 64);
        if (tid >= off) incl += t;
      }
      base[c * 64 + tid] = carry + incl - v;
      carry += __shfl(incl, 63, 64);
    }
  }
  __syncthreads();
  if (tid < nbins && cnt[tid] > 0) gbase[tid] = atomicAdd(&gcur[tid], cnt[tid]);
  cur[tid] = base[tid];
  __syncthreads();
  for (int i = tid; i < ne; i += 256) {
    int d = dst[e0 + i], s = src[e0 + i];
    int p = atomicAdd(&cur[d >> BIN_SHIFT], 1);
    stage[p] = make_uint2((unsigned)d, (unsigned)s);
  }
  __syncthreads();
  for (int i = tid; i < ne; i += 256) {
    uint2 en = stage[i];
    int b = en.x >> BIN_SHIFT;
    int gi = gbase[b] + (i - base[b]);
    if (gi < CAPB) binbuf[(size_t)b * CAPB + gi] = en;
  }
}

// ---------------- pass B: per-bin deg/dis/start + col fill, all dense writes ----------------
__global__ __launch_bounds__(256) void k_passB(
    const uint2* __restrict__ binbuf, const int* __restrict__ gcur,
    int* __restrict__ deg, float* __restrict__ dis, int* __restrict__ start,
    int* __restrict__ col, int N, int nbins) {
  __shared__ int hist[512], lstart[512], cur[512];
  __shared__ int colstage[CAPB];                     // 48 KB
  __shared__ int binbase_s;
  int b = blockIdx.x, tid = threadIdx.x;
  int node0 = b << BIN_SHIFT;
  int cnt = min(gcur[b], CAPB);
  hist[tid] = 0; hist[tid + 256] = 0;
  __syncthreads();
  const uint2* bp = binbuf + (size_t)b * CAPB;
  for (int i = tid; i < cnt; i += 256) atomicAdd(&hist[bp[i].x & (BIN_NODES - 1)], 1);
  __syncthreads();
  if (tid < 64) {
    // binbase = sum of capped counts of previous bins
    int s = 0;
    for (int i = tid; i < b; i += 64) s += min(gcur[i], CAPB);
#pragma unroll
    for (int off = 32; off; off >>= 1) s += __shfl_xor(s, off, 64);
    if (tid == 0) binbase_s = s;
    // exclusive scan hist[512] -> lstart (8 chunks of 64)
    int carry = 0;
#pragma unroll
    for (int c = 0; c < 8; ++c) {
      int v = hist[c * 64 + tid];
      int incl = v;
#pragma unroll
      for (int off = 1; off < 64; off <<= 1) {
        int t = __shfl_up(incl, off, 64);
        if (tid >= off) incl += t;
      }
      lstart[c * 64 + tid] = carry + incl - v;
      carry += __shfl(incl, 63, 64);
    }
  }
  __syncthreads();
  int binbase = binbase_s;
  for (int i = tid; i < 512; i += 256) {
    int node = node0 + i;
    if (node < N) {
      int dg = hist[i];
      deg[node] = dg;
      dis[node] = rsqrtf((float)(dg + 1));
      start[node] = binbase + lstart[i];
    }
  }
  cur[tid] = lstart[tid]; cur[tid + 256] = lstart[tid + 256];
  __syncthreads();
  for (int i = tid; i < cnt; i += 256) {
    uint2 en = bp[i];
    int p = atomicAdd(&cur[en.x & (BIN_NODES - 1)], 1);
    colstage[p] = (int)en.y;
  }
  __syncthreads();
  for (int i = tid; i < cnt; i += 256) col[binbase + i] = colstage[i];
}

// ---------------- merged weight prep: split W1,W2; fold+split head ----------------
__global__ void k_prep(const float* __restrict__ W1, const float* __restrict__ W2,
                       const float* __restrict__ Wp1, const float* __restrict__ Wp2,
                       const float* __restrict__ bp1, const float* __restrict__ bp2,
                       us* __restrict__ Wt1h, us* __restrict__ Wt1l,
                       us* __restrict__ Wt2h, us* __restrict__ Wt2l,
                       us* __restrict__ Wch, us* __restrict__ Wcl, float* __restrict__ bc) {
  int blk = blockIdx.x, tid = threadIdx.x;
  if (blk < 128) {
    const float* W = (blk < 64) ? W1 : W2;
    us* Wh = (blk < 64) ? Wt1h : Wt2h;
    us* Wl = (blk < 64) ? Wt1l : Wt2l;
    int idx = (blk & 63) * 256 + tid;   // 16384
    int k = idx >> 7, n = idx & 127;
    us h, l;
    split2(W[idx], h, l);
    Wh[n * 128 + k] = h;
    Wl[n * 128 + k] = l;
  } else if (blk < 160) {
    int idx = (blk - 128) * 256 + tid;  // 8192
    int k = idx >> 6, j = idx & 63;
    float acc = 0.f;
    for (int t = 0; t < 128; ++t) acc += Wp1[k * 128 + t] * Wp2[t * 64 + j];
    us h, l;
    split2(acc, h, l);
    Wch[j * 128 + k] = h;
    Wcl[j * 128 + k] = l;
  } else {
    int j = tid;
    if (j < 64) {
      float acc = bp2[j];
      for (int t = 0; t < 128; ++t) acc += bp1[t] * Wp2[t * 64 + j];
      bc[j] = acc;
    }
  }
}

// ---------------- shared device routine: aggregate NPW rows per wave into LDS tile ----------------
// Per node: self + neighbor rows of h (bf16, (N+1) rows with row N zeroed), col preloaded into
// a lane register and broadcast via readlane (scalar-base gathers, 4 independent streams),
// finalize relu(agg*dis + bias) -> rne bf16 -> As[r*136 + 2*lane] (2 channels per lane).
__device__ __forceinline__ void gather_rows_to_lds(
    const us* __restrict__ h, us* __restrict__ As, int row0, int wave, int lane, int NPW,
    const int* __restrict__ start, const int* __restrict__ deg, const int* __restrict__ col,
    const float* __restrict__ dis, const float* __restrict__ bias, int N) {
  const uint32_t* h1 = (const uint32_t*)h;
  float2 bb = ((const float2*)bias)[lane];
  for (int i = 0; i < NPW; ++i) {
    int r = wave * NPW + i;
    int node = row0 + r;
    bool valid = node < N;
    int nd = valid ? node : N;
    uint32_t u = h1[(size_t)nd * 64 + lane];     // self row (zero row if OOB)
    float a0 = bflo(u), b0 = bfhi(u);
    float a1 = 0.f, b1 = 0.f, a2 = 0.f, b2 = 0.f, a3 = 0.f, b3 = 0.f;
    int e0 = valid ? start[node] : 0;
    int dg = valid ? deg[node] : 0;
    int myc = (lane < dg) ? col[e0 + lane] : N;  // N = zero row (dummy)
    int dgm = min(dg, 64);
    for (int k = 0; k < dgm; k += 4) {
      int c0 = __builtin_amdgcn_readlane(myc, k);
      int c1 = __builtin_amdgcn_readlane(myc, k + 1);
      int c2 = __builtin_amdgcn_readlane(myc, k + 2);
      int c3 = __builtin_amdgcn_readlane(myc, k + 3);
      uint32_t u0 = h1[(size_t)c0 * 64 + lane];
      uint32_t u1 = h1[(size_t)c1 * 64 + lane];
      uint32_t u2 = h1[(size_t)c2 * 64 + lane];
      uint32_t u3 = h1[(size_t)c3 * 64 + lane];
      a0 += bflo(u0); b0 += bfhi(u0);
      a1 += bflo(u1); b1 += bfhi(u1);
      a2 += bflo(u2); b2 += bfhi(u2);
      a3 += bflo(u3); b3 += bfhi(u3);
    }
    // extremely rare deg > 64 fallback (Poisson mean 16)
    for (int e = e0 + 64; e < e0 + dg; ++e) {
      uint32_t u0 = h1[(size_t)col[e] * 64 + lane];
      a0 += bflo(u0); b0 += bfhi(u0);
    }
    float sc = valid ? dis[node] : 0.f;
    float rx = fmaxf((a0 + a1 + a2 + a3) * sc + bb.x, 0.f);
    float ry = fmaxf((b0 + b1 + b2 + b3) * sc + bb.y, 0.f);
    *(uint32_t*)&As[r * 136 + 2 * lane] =
        ((uint32_t)f32_to_bf16_rne(ry) << 16) | f32_to_bf16_rne(rx);
  }
}

// ---------------- layer-1 GEMM: hbuf1[row][128] = rne_bf16(dis[row] * (x @ W1)) ----------------
// x staged as rne-bf16 (hi only); W kept hi+lo -> 2 MFMA per k-chunk.
__global__ __launch_bounds__(256) void k_gemm1(
    const float* __restrict__ A, const us* __restrict__ Wh,
    const us* __restrict__ Wl, const float* __restrict__ dis,
    us* __restrict__ out_bf16, int N, int ntiles) {
  __shared__ us As[32 * 136];
  int tid = threadIdx.x;
  int wave = tid >> 6, lane = tid & 63;
  int n0 = wave * 32;
  int nn = n0 + (lane & 31);
  int khalf = (lane >> 5) * 8;
  int m = lane & 31;

  short8 bh[8], bl[8];
#pragma unroll
  for (int c = 0; c < 8; ++c) {
    bh[c] = *(const short8*)&Wh[nn * 128 + c * 16 + khalf];
    bl[c] = *(const short8*)&Wl[nn * 128 + c * 16 + khalf];
  }

  for (int t = blockIdx.x; t < ntiles; t += gridDim.x) {
    int row0 = t * 32;
    __syncthreads();
    for (int j = tid; j < 1024; j += 256) {
      int r = j >> 5, c = j & 31;
      int row = row0 + r;
      float4 v = make_float4(0.f, 0.f, 0.f, 0.f);
      if (row < N) v = *(const float4*)&A[(size_t)row * 128 + c * 4];
      *(ushort4*)&As[r * 136 + c * 4] = make_ushort4(
          f32_to_bf16_rne(v.x), f32_to_bf16_rne(v.y),
          f32_to_bf16_rne(v.z), f32_to_bf16_rne(v.w));
    }
    __syncthreads();

    f32x16 acc = {};
#pragma unroll
    for (int c = 0; c < 8; ++c) {
      short8 ah = *(const short8*)&As[m * 136 + c * 16 + khalf];
      acc = __builtin_amdgcn_mfma_f32_32x32x16_bf16(ah, bh[c], acc, 0, 0, 0);
      acc = __builtin_amdgcn_mfma_f32_32x32x16_bf16(ah, bl[c], acc, 0, 0, 0);
    }

    int col = n0 + (lane & 31);
    int rbase = row0 + 4 * (lane >> 5);
#pragma unroll
    for (int reg = 0; reg < 16; ++reg) {
      int row = rbase + (reg & 3) + 8 * (reg >> 2);
      if (row < N) {
        float v = acc[reg] * dis[row];
        out_bf16[(size_t)row * 128 + col] = f32_to_bf16_rne(v);
      }
    }
  }
}

// ---------------- fused layer-2: gather(h1)+bias+relu -> LDS -> GEMM(W2) -> hbuf2 ----------------
__global__ __launch_bounds__(256) void k_gcn2(
    const us* __restrict__ h, const us* __restrict__ Wh, const us* __restrict__ Wl,
    const int* __restrict__ start, const int* __restrict__ deg,
    const int* __restrict__ col, const float* __restrict__ dis,
    const float* __restrict__ bias, us* __restrict__ out_bf16, int N, int ntiles) {
  __shared__ us As[32 * 136];
  int tid = threadIdx.x;
  int wave = tid >> 6, lane = tid & 63;
  int n0 = wave * 32;
  int nn = n0 + (lane & 31);
  int khalf = (lane >> 5) * 8;
  int m = lane & 31;

  short8 bh[8], bl[8];
#pragma unroll
  for (int c = 0; c < 8; ++c) {
    bh[c] = *(const short8*)&Wh[nn * 128 + c * 16 + khalf];
    bl[c] = *(const short8*)&Wl[nn * 128 + c * 16 + khalf];
  }

  for (int t = blockIdx.x; t < ntiles; t += gridDim.x) {
    int row0 = t * 32;
    __syncthreads();
    gather_rows_to_lds(h, As, row0, wave, lane, 8, start, deg, col, dis, bias, N);
    __syncthreads();

    f32x16 acc = {};
#pragma unroll
    for (int c = 0; c < 8; ++c) {
      short8 ah = *(const short8*)&As[m * 136 + c * 16 + khalf];
      acc = __builtin_amdgcn_mfma_f32_32x32x16_bf16(ah, bh[c], acc, 0, 0, 0);
      acc = __builtin_amdgcn_mfma_f32_32x32x16_bf16(ah, bl[c], acc, 0, 0, 0);
    }

    int col_o = n0 + (lane & 31);
    int rbase = row0 + 4 * (lane >> 5);
#pragma unroll
    for (int reg = 0; reg < 16; ++reg) {
      int row = rbase + (reg & 3) + 8 * (reg >> 2);
      if (row < N) {
        float v = acc[reg] * dis[row];
        out_bf16[(size_t)row * 128 + col_o] = f32_to_bf16_rne(v);
      }
    }
  }
}

// ---------------- fused head: gather(h2)+bias+relu -> LDS -> GEMM(Wc) -> log_softmax -> out ----------------
__global__ __launch_bounds__(256) void k_gcnhead(
    const us* __restrict__ h, const us* __restrict__ Wch, const us* __restrict__ Wcl,
    const int* __restrict__ start, const int* __restrict__ deg,
    const int* __restrict__ col, const float* __restrict__ dis,
    const float* __restrict__ bias, const float* __restrict__ bc,
    float* __restrict__ out, int N, int ntiles) {
  __shared__ us As[64 * 136];
  __shared__ float red[2][2][64];
  int tid = threadIdx.x;
  int wave = tid >> 6, lane = tid & 63;
  int rt = wave >> 1, ct = wave & 1;
  int colj = ct * 32 + (lane & 31);
  int khalf = (lane >> 5) * 8;
  int m = lane & 31;

  short8 bh[8], bl[8];
#pragma unroll
  for (int c = 0; c < 8; ++c) {
    bh[c] = *(const short8*)&Wch[colj * 128 + c * 16 + khalf];
    bl[c] = *(const short8*)&Wcl[colj * 128 + c * 16 + khalf];
  }
  float bcv = bc[colj];

  for (int t = blockIdx.x; t < ntiles; t += gridDim.x) {
    int row0 = t * 64;
    __syncthreads();
    gather_rows_to_lds(h, As, row0, wave, lane, 16, start, deg, col, dis, bias, N);
    __syncthreads();

    f32x16 acc = {};
    int mrow = rt * 32 + m;
#pragma unroll
    for (int c = 0; c < 8; ++c) {
      short8 ah = *(const short8*)&As[mrow * 136 + c * 16 + khalf];
      acc = __builtin_amdgcn_mfma_f32_32x32x16_bf16(ah, bh[c], acc, 0, 0, 0);
      acc = __builtin_amdgcn_mfma_f32_32x32x16_bf16(ah, bl[c], acc, 0, 0, 0);
    }

    float lg[16], mx[16];
#pragma unroll
    for (int reg = 0; reg < 16; ++reg) {
      lg[reg] = acc[reg] + bcv;
      float v = lg[reg];
#pragma unroll
      for (int off = 16; off > 0; off >>= 1) v = fmaxf(v, __shfl_xor(v, off, 32));
      mx[reg] = v;
    }
    if ((lane & 31) == 0) {
#pragma unroll
      for (int reg = 0; reg < 16; ++reg) {
        int rl = rt * 32 + (reg & 3) + 8 * (reg >> 2) + 4 * (lane >> 5);
        red[0][ct][rl] = mx[reg];
      }
    }
    __syncthreads();

    float ex[16], sm[16];
#pragma unroll
    for (int reg = 0; reg < 16; ++reg) {
      int rl = rt * 32 + (reg & 3) + 8 * (reg >> 2) + 4 * (lane >> 5);
      float rmax = fmaxf(red[0][0][rl], red[0][1][rl]);
      ex[reg] = lg[reg] - rmax;
      float v = expf(ex[reg]);
#pragma unroll
      for (int off = 16; off > 0; off >>= 1) v += __shfl_xor(v, off, 32);
      sm[reg] = v;
    }
    if ((lane & 31) == 0) {
#pragma unroll
      for (int reg = 0; reg < 16; ++reg) {
        int rl = rt * 32 + (reg & 3) + 8 * (reg >> 2) + 4 * (lane >> 5);
        red[1][ct][rl] = sm[reg];
      }
    }
    __syncthreads();

#pragma unroll
    for (int reg = 0; reg < 16; ++reg) {
      int rl = rt * 32 + (reg & 3) + 8 * (reg >> 2) + 4 * (lane >> 5);
      int row = row0 + rl;
      if (row < N) {
        float total = red[1][0][rl] + red[1][1][rl];
        out[(size_t)row * 64 + colj] = ex[reg] - logf(total);
      }
    }
  }
}

extern "C" void kernel_launch(void* const* d_in, const int* in_sizes, int n_in,
                              void* d_out, int out_size, void* d_ws, size_t ws_size,
                              hipStream_t stream) {
  const float* x   = (const float*)d_in[0];
  const int*   ei  = (const int*)d_in[1];
  const float* W1  = (const float*)d_in[2];
  const float* b1  = (const float*)d_in[3];
  const float* W2  = (const float*)d_in[4];
  const float* b2  = (const float*)d_in[5];
  const float* Wp1 = (const float*)d_in[6];
  const float* bp1 = (const float*)d_in[7];
  const float* Wp2 = (const float*)d_in[8];
  const float* bp2 = (const float*)d_in[9];
  float* out = (float*)d_out;

  int N = in_sizes[0] / 128;
  int E = in_sizes[1] / 2;
  const int* src = ei;
  const int* dst = ei + E;
  int nbins = (N + BIN_NODES - 1) >> BIN_SHIFT;

  // workspace layout (int granularity)
  float* dis   = (float*)d_ws;                    // N
  int*   deg   = (int*)(dis + N);                 // N
  int*   start = deg + N;                         // N
  int*   col   = start + N;                       // E
  int*   gcur  = col + ((E + 3) & ~3);            // 256 (zeroed)
  us* Wt1h = (us*)(gcur + 256);                   // 16384 each
  us* Wt1l = Wt1h + 16384;
  us* Wt2h = Wt1l + 16384;
  us* Wt2l = Wt2h + 16384;
  us* Wch  = Wt2l + 16384;                        // 8192
  us* Wcl  = Wch + 8192;                          // 8192
  float* bc = (float*)(Wcl + 8192);               // 64 (+pad)
  uint2* binbuf = (uint2*)(bc + 80);              // nbins*CAPB uint2 (~19.3 MB)
  us* hbuf1 = (us*)(binbuf + (size_t)nbins * CAPB);  // (N+1)*128 bf16 (+ zero row)
  us* hbuf2 = hbuf1 + (size_t)(N + 1) * 128;         // (N+1)*128 bf16 (+ zero row)

  hipMemsetAsync(gcur, 0, 256 * sizeof(int), stream);
  hipMemsetAsync(hbuf1 + (size_t)N * 128, 0, 128 * sizeof(us), stream);  // zero row 1
  hipMemsetAsync(hbuf2 + (size_t)N * 128, 0, 128 * sizeof(us), stream);  // zero row 2

  int ablocks = (E + EPB - 1) / EPB;
  k_binA<<<ablocks, 256, 0, stream>>>(src, dst, binbuf, gcur, E, nbins);
  k_passB<<<nbins, 256, 0, stream>>>(binbuf, gcur, deg, dis, start, col, N, nbins);
  k_prep<<<161, 256, 0, stream>>>(W1, W2, Wp1, Wp2, bp1, bp2,
                                  Wt1h, Wt1l, Wt2h, Wt2l, Wch, Wcl, bc);

  int ntiles32 = (N + 31) / 32;
  int ntiles64 = (N + 63) / 64;
  int g32 = ntiles32 < 1024 ? ntiles32 : 1024;
  int g64 = ntiles64 < 1024 ? ntiles64 : 1024;

  // layer 1 transform
  k_gemm1<<<g32, 256, 0, stream>>>(x, Wt1h, Wt1l, dis, hbuf1, N, ntiles32);
  // layer 1 aggregate + layer 2 transform (fused)
  k_gcn2<<<g32, 256, 0, stream>>>(hbuf1, Wt2h, Wt2l, start, deg, col, dis, b1,
                                  hbuf2, N, ntiles32);
  // layer 2 aggregate + folded head + log_softmax (fused)
  k_gcnhead<<<g64, 256, 0, stream>>>(hbuf2, Wch, Wcl, start, deg, col, dis, b2,
                                     bc, out, N, ntiles64);
}

// Round 5
// 397.802 us; speedup vs baseline: 1.4181x; 1.4181x over previous
//
#include <hip/hip_runtime.h>
#include <hip/hip_bf16.h>
#include <cstdint>

typedef __attribute__((ext_vector_type(8))) short short8;     // 8 bf16 frag (4 VGPRs)
typedef __attribute__((ext_vector_type(16))) float f32x16;    // 32x32 accumulator
typedef unsigned short us;

#define BIN_SHIFT 9
#define BIN_NODES 512
#define CAPB 12288   // per-bin capacity (mean 8163, +45 sigma)
#define EPB 4096     // edges per binA block

__device__ __forceinline__ float bflo(uint32_t u) { return __builtin_bit_cast(float, u << 16); }
__device__ __forceinline__ float bfhi(uint32_t u) { return __builtin_bit_cast(float, u & 0xffff0000u); }

__device__ __forceinline__ us f32_to_bf16_rne(float f) {
  uint32_t u = __builtin_bit_cast(uint32_t, f);
  u += 0x7fffu + ((u >> 16) & 1u);
  return (us)(u >> 16);
}

// split f32 into truncated-bf16 hi + bf16 lo (residual); hi+lo ~= f to ~2^-16 rel
__device__ __forceinline__ void split2(float f, us& h, us& l) {
  uint32_t u = __builtin_bit_cast(uint32_t, f);
  h = (us)(u >> 16);
  float fh = __builtin_bit_cast(float, u & 0xffff0000u);
  float r = f - fh;  // exact
  l = (us)(__builtin_bit_cast(uint32_t, r) >> 16);
}

// ---------------- merged weight prep + workspace init (runs FIRST, replaces memsets) ------------
__global__ void k_prep(const float* __restrict__ W1, const float* __restrict__ W2,
                       const float* __restrict__ Wp1, const float* __restrict__ Wp2,
                       const float* __restrict__ bp1, const float* __restrict__ bp2,
                       us* __restrict__ Wt1h, us* __restrict__ Wt1l,
                       us* __restrict__ Wt2h, us* __restrict__ Wt2l,
                       us* __restrict__ Wch, us* __restrict__ Wcl, float* __restrict__ bc,
                       int* __restrict__ gcur, int* __restrict__ hzero) {
  int blk = blockIdx.x, tid = threadIdx.x;
  if (blk < 128) {
    const float* W = (blk < 64) ? W1 : W2;
    us* Wh = (blk < 64) ? Wt1h : Wt2h;
    us* Wl = (blk < 64) ? Wt1l : Wt2l;
    int idx = (blk & 63) * 256 + tid;   // 16384
    int k = idx >> 7, n = idx & 127;
    us h, l;
    split2(W[idx], h, l);
    Wh[n * 128 + k] = h;
    Wl[n * 128 + k] = l;
  } else if (blk < 160) {
    int idx = (blk - 128) * 256 + tid;  // 8192
    int k = idx >> 6, j = idx & 63;
    float acc = 0.f;
    for (int t = 0; t < 128; ++t) acc += Wp1[k * 128 + t] * Wp2[t * 64 + j];
    us h, l;
    split2(acc, h, l);
    Wch[j * 128 + k] = h;
    Wcl[j * 128 + k] = l;
  } else {
    // workspace init (replaces two hipMemsetAsync dispatches)
    gcur[tid] = 0;
    if (tid < 64) {
      hzero[tid] = 0;  // zero dummy row at hbuf[N]
      float acc = bp2[tid];
      for (int t = 0; t < 128; ++t) acc += bp1[t] * Wp2[t * 64 + tid];
      bc[tid] = acc;
    }
  }
}

// ---------------- pass A: bin (dst,src) pairs by dst>>9 with dense batched appends ----------------
__global__ __launch_bounds__(256) void k_binA(
    const int* __restrict__ src, const int* __restrict__ dst,
    uint2* __restrict__ binbuf, int* __restrict__ gcur, int E, int nbins) {
  __shared__ uint2 stage[EPB];                       // 32 KB
  __shared__ int cnt[256], base[256], cur[256], gbase[256];
  int tid = threadIdx.x;
  int e0 = blockIdx.x * EPB;
  int ne = min(EPB, E - e0);
  if (ne <= 0) return;
  cnt[tid] = 0;
  __syncthreads();
  for (int i = tid; i < ne; i += 256) atomicAdd(&cnt[dst[e0 + i] >> BIN_SHIFT], 1);
  __syncthreads();
  // exclusive scan cnt[256] -> base (wave 0, 4 chunks of 64)
  if (tid < 64) {
    int carry = 0;
#pragma unroll
    for (int c = 0; c < 4; ++c) {
      int v = cnt[c * 64 + tid];
      int incl = v;
#pragma unroll
      for (int off = 1; off < 64; off <<= 1) {
        int t = __shfl_up(incl, off, 64);
        if (tid >= off) incl += t;
      }
      base[c * 64 + tid] = carry + incl - v;
      carry += __shfl(incl, 63, 64);
    }
  }
  __syncthreads();
  if (tid < nbins && cnt[tid] > 0) gbase[tid] = atomicAdd(&gcur[tid], cnt[tid]);
  cur[tid] = base[tid];
  __syncthreads();
  for (int i = tid; i < ne; i += 256) {
    int d = dst[e0 + i], s = src[e0 + i];
    int p = atomicAdd(&cur[d >> BIN_SHIFT], 1);
    stage[p] = make_uint2((unsigned)d, (unsigned)s);
  }
  __syncthreads();
  for (int i = tid; i < ne; i += 256) {
    uint2 en = stage[i];
    int b = en.x >> BIN_SHIFT;
    int gi = gbase[b] + (i - base[b]);
    if (gi < CAPB) binbuf[(size_t)b * CAPB + gi] = en;
  }
}

// ---------------- pass B: per-bin deg/dis/start + col fill, all dense writes ----------------
__global__ __launch_bounds__(256) void k_passB(
    const uint2* __restrict__ binbuf, const int* __restrict__ gcur,
    int* __restrict__ deg, float* __restrict__ dis, int* __restrict__ start,
    int* __restrict__ col, int N, int nbins) {
  __shared__ int hist[512], lstart[512], cur[512];
  __shared__ int colstage[CAPB];                     // 48 KB
  __shared__ int binbase_s;
  int b = blockIdx.x, tid = threadIdx.x;
  int node0 = b << BIN_SHIFT;
  int cnt = min(gcur[b], CAPB);
  hist[tid] = 0; hist[tid + 256] = 0;
  __syncthreads();
  const uint2* bp = binbuf + (size_t)b * CAPB;
  for (int i = tid; i < cnt; i += 256) atomicAdd(&hist[bp[i].x & (BIN_NODES - 1)], 1);
  __syncthreads();
  if (tid < 64) {
    // binbase = sum of capped counts of previous bins
    int s = 0;
    for (int i = tid; i < b; i += 64) s += min(gcur[i], CAPB);
#pragma unroll
    for (int off = 32; off; off >>= 1) s += __shfl_xor(s, off, 64);
    if (tid == 0) binbase_s = s;
    // exclusive scan hist[512] -> lstart (8 chunks of 64)
    int carry = 0;
#pragma unroll
    for (int c = 0; c < 8; ++c) {
      int v = hist[c * 64 + tid];
      int incl = v;
#pragma unroll
      for (int off = 1; off < 64; off <<= 1) {
        int t = __shfl_up(incl, off, 64);
        if (tid >= off) incl += t;
      }
      lstart[c * 64 + tid] = carry + incl - v;
      carry += __shfl(incl, 63, 64);
    }
  }
  __syncthreads();
  int binbase = binbase_s;
  for (int i = tid; i < 512; i += 256) {
    int node = node0 + i;
    if (node < N) {
      int dg = hist[i];
      deg[node] = dg;
      dis[node] = rsqrtf((float)(dg + 1));
      start[node] = binbase + lstart[i];
    }
  }
  cur[tid] = lstart[tid]; cur[tid + 256] = lstart[tid + 256];
  __syncthreads();
  for (int i = tid; i < cnt; i += 256) {
    uint2 en = bp[i];
    int p = atomicAdd(&cur[en.x & (BIN_NODES - 1)], 1);
    colstage[p] = (int)en.y;
  }
  __syncthreads();
  for (int i = tid; i < cnt; i += 256) col[binbase + i] = colstage[i];
}

// ---------------- layer-1 GEMM: hbuf[row][128] = rne_bf16(dis[row] * (x @ W1)) ----------------
// x staged as rne-bf16 (hi only, validated); W kept hi+lo -> 2 MFMA per k-chunk.
__global__ __launch_bounds__(256) void k_gemm1(
    const float* __restrict__ A, const us* __restrict__ Wh,
    const us* __restrict__ Wl, const float* __restrict__ dis,
    us* __restrict__ out_bf16, int N, int ntiles) {
  __shared__ us As[32 * 136];
  int tid = threadIdx.x;
  int wave = tid >> 6, lane = tid & 63;
  int n0 = wave * 32;
  int nn = n0 + (lane & 31);
  int khalf = (lane >> 5) * 8;
  int m = lane & 31;

  short8 bh[8], bl[8];
#pragma unroll
  for (int c = 0; c < 8; ++c) {
    bh[c] = *(const short8*)&Wh[nn * 128 + c * 16 + khalf];
    bl[c] = *(const short8*)&Wl[nn * 128 + c * 16 + khalf];
  }

  for (int t = blockIdx.x; t < ntiles; t += gridDim.x) {
    int row0 = t * 32;
    __syncthreads();
    for (int j = tid; j < 1024; j += 256) {
      int r = j >> 5, c = j & 31;
      int row = row0 + r;
      float4 v = make_float4(0.f, 0.f, 0.f, 0.f);
      if (row < N) v = *(const float4*)&A[(size_t)row * 128 + c * 4];
      *(ushort4*)&As[r * 136 + c * 4] = make_ushort4(
          f32_to_bf16_rne(v.x), f32_to_bf16_rne(v.y),
          f32_to_bf16_rne(v.z), f32_to_bf16_rne(v.w));
    }
    __syncthreads();

    f32x16 acc = {};
#pragma unroll
    for (int c = 0; c < 8; ++c) {
      short8 ah = *(const short8*)&As[m * 136 + c * 16 + khalf];
      acc = __builtin_amdgcn_mfma_f32_32x32x16_bf16(ah, bh[c], acc, 0, 0, 0);
      acc = __builtin_amdgcn_mfma_f32_32x32x16_bf16(ah, bl[c], acc, 0, 0, 0);
    }

    int col = n0 + (lane & 31);
    int rbase = row0 + 4 * (lane >> 5);
#pragma unroll
    for (int reg = 0; reg < 16; ++reg) {
      int row = rbase + (reg & 3) + 8 * (reg >> 2);
      if (row < N) {
        float v = acc[reg] * dis[row];
        out_bf16[(size_t)row * 128 + col] = f32_to_bf16_rne(v);
      }
    }
  }
}

// ---------------- layer-2 GEMM: hbuf[row][128] = rne_bf16(dis[row] * (act @ W2)) ----------------
__global__ __launch_bounds__(256) void k_gemm2(
    const us* __restrict__ A, const us* __restrict__ Wh,
    const us* __restrict__ Wl, const float* __restrict__ dis,
    us* __restrict__ out_bf16, int N, int ntiles) {
  __shared__ us As[32 * 136];
  int tid = threadIdx.x;
  int wave = tid >> 6, lane = tid & 63;
  int n0 = wave * 32;
  int nn = n0 + (lane & 31);
  int khalf = (lane >> 5) * 8;
  int m = lane & 31;

  short8 bh[8], bl[8];
#pragma unroll
  for (int c = 0; c < 8; ++c) {
    bh[c] = *(const short8*)&Wh[nn * 128 + c * 16 + khalf];
    bl[c] = *(const short8*)&Wl[nn * 128 + c * 16 + khalf];
  }

  for (int t = blockIdx.x; t < ntiles; t += gridDim.x) {
    int row0 = t * 32;
    __syncthreads();
    for (int j = tid; j < 512; j += 256) {
      int r = j >> 4, c = j & 15;
      int row = row0 + r;
      uint4 v = make_uint4(0u, 0u, 0u, 0u);
      if (row < N) v = *(const uint4*)&A[(size_t)row * 128 + c * 8];
      *(uint4*)&As[r * 136 + c * 8] = v;
    }
    __syncthreads();

    f32x16 acc = {};
#pragma unroll
    for (int c = 0; c < 8; ++c) {
      short8 ah = *(const short8*)&As[m * 136 + c * 16 + khalf];
      acc = __builtin_amdgcn_mfma_f32_32x32x16_bf16(ah, bh[c], acc, 0, 0, 0);
      acc = __builtin_amdgcn_mfma_f32_32x32x16_bf16(ah, bl[c], acc, 0, 0, 0);
    }

    int col = n0 + (lane & 31);
    int rbase = row0 + 4 * (lane >> 5);
#pragma unroll
    for (int reg = 0; reg < 16; ++reg) {
      int row = rbase + (reg & 3) + 8 * (reg >> 2);
      if (row < N) {
        float v = acc[reg] * dis[row];
        out_bf16[(size_t)row * 128 + col] = f32_to_bf16_rne(v);
      }
    }
  }
}

// ---------------- gather-aggregate (bf16 in) + fused finalize -> bf16 out ----------------
// One 64-lane wave per node (4B = 2 channels per lane), 8 waves/block. col entries preloaded
// into one register and broadcast via readlane (scalar base addressing, col load off critical
// path). Lanes past deg point at the zeroed dummy row at index N (L1-hot), so the 8-chunk loop
// is uniform with no tail and 8 independent gathers in flight per wave.
__global__ __launch_bounds__(512) void k_gather(
    const us* __restrict__ h, us* __restrict__ o,
    const int* __restrict__ start, const int* __restrict__ deg,
    const int* __restrict__ col, const float* __restrict__ dis,
    const float* __restrict__ bias, int N) {
  int wave = threadIdx.x >> 6, lane = threadIdx.x & 63;
  int node = blockIdx.x * 8 + wave;
  if (node >= N) return;
  const uint32_t* h1 = (const uint32_t*)h;
  uint32_t u = h1[(size_t)node * 64 + lane];     // self row
  float a0 = bflo(u), b0 = bfhi(u);
  float a1 = 0.f, b1 = 0.f, a2 = 0.f, b2 = 0.f, a3 = 0.f, b3 = 0.f;
  float a4 = 0.f, b4 = 0.f, a5 = 0.f, b5 = 0.f, a6 = 0.f, b6 = 0.f, a7 = 0.f, b7 = 0.f;
  int e0 = start[node];
  int dg = deg[node];
  int myc = (lane < dg) ? col[e0 + lane] : N;    // N = zero row (dummy)
  int dgm = min(dg, 64);
  for (int k = 0; k < dgm; k += 8) {
    int c0 = __builtin_amdgcn_readlane(myc, k);
    int c1 = __builtin_amdgcn_readlane(myc, k + 1);
    int c2 = __builtin_amdgcn_readlane(myc, k + 2);
    int c3 = __builtin_amdgcn_readlane(myc, k + 3);
    int c4 = __builtin_amdgcn_readlane(myc, k + 4);
    int c5 = __builtin_amdgcn_readlane(myc, k + 5);
    int c6 = __builtin_amdgcn_readlane(myc, k + 6);
    int c7 = __builtin_amdgcn_readlane(myc, k + 7);
    uint32_t u0 = h1[(size_t)c0 * 64 + lane];
    uint32_t u1 = h1[(size_t)c1 * 64 + lane];
    uint32_t u2 = h1[(size_t)c2 * 64 + lane];
    uint32_t u3 = h1[(size_t)c3 * 64 + lane];
    uint32_t u4 = h1[(size_t)c4 * 64 + lane];
    uint32_t u5 = h1[(size_t)c5 * 64 + lane];
    uint32_t u6 = h1[(size_t)c6 * 64 + lane];
    uint32_t u7 = h1[(size_t)c7 * 64 + lane];
    a0 += bflo(u0); b0 += bfhi(u0);
    a1 += bflo(u1); b1 += bfhi(u1);
    a2 += bflo(u2); b2 += bfhi(u2);
    a3 += bflo(u3); b3 += bfhi(u3);
    a4 += bflo(u4); b4 += bfhi(u4);
    a5 += bflo(u5); b5 += bfhi(u5);
    a6 += bflo(u6); b6 += bfhi(u6);
    a7 += bflo(u7); b7 += bfhi(u7);
  }
  // extremely rare deg > 64 fallback (Poisson mean 16)
  for (int e = e0 + 64; e < e0 + dg; ++e) {
    uint32_t u0 = h1[(size_t)col[e] * 64 + lane];
    a0 += bflo(u0); b0 += bfhi(u0);
  }
  float sc = dis[node];
  float2 bb = ((const float2*)bias)[lane];
  float ax = ((a0 + a1) + (a2 + a3)) + ((a4 + a5) + (a6 + a7));
  float ay = ((b0 + b1) + (b2 + b3)) + ((b4 + b5) + (b6 + b7));
  float rx = fmaxf(ax * sc + bb.x, 0.f);
  float ry = fmaxf(ay * sc + bb.y, 0.f);
  ((uint32_t*)o)[(size_t)node * 64 + lane] =
      ((uint32_t)f32_to_bf16_rne(ry) << 16) | f32_to_bf16_rne(rx);
}

// ---------------- head: out = log_softmax(act @ Wc + bc) via MFMA, fused softmax ----------------
__global__ __launch_bounds__(256) void k_head_mfma(
    const us* __restrict__ act, const us* __restrict__ Wch,
    const us* __restrict__ Wcl, const float* __restrict__ bc,
    float* __restrict__ out, int N) {
  __shared__ us As[64 * 136];
  __shared__ float red[2][2][64];
  int tid = threadIdx.x;
  int wave = tid >> 6, lane = tid & 63;
  int rt = wave >> 1, ct = wave & 1;
  int colj = ct * 32 + (lane & 31);
  int khalf = (lane >> 5) * 8;
  int m = lane & 31;

  short8 bh[8], bl[8];
#pragma unroll
  for (int c = 0; c < 8; ++c) {
    bh[c] = *(const short8*)&Wch[colj * 128 + c * 16 + khalf];
    bl[c] = *(const short8*)&Wcl[colj * 128 + c * 16 + khalf];
  }

  int row0 = blockIdx.x * 64;
  for (int j = tid; j < 1024; j += 256) {
    int r = j >> 4, c = j & 15;
    int row = row0 + r;
    uint4 v = make_uint4(0u, 0u, 0u, 0u);
    if (row < N) v = *(const uint4*)&act[(size_t)row * 128 + c * 8];
    *(uint4*)&As[r * 136 + c * 8] = v;
  }
  __syncthreads();

  f32x16 acc = {};
  int mrow = rt * 32 + m;
#pragma unroll
  for (int c = 0; c < 8; ++c) {
    short8 ah = *(const short8*)&As[mrow * 136 + c * 16 + khalf];
    acc = __builtin_amdgcn_mfma_f32_32x32x16_bf16(ah, bh[c], acc, 0, 0, 0);
    acc = __builtin_amdgcn_mfma_f32_32x32x16_bf16(ah, bl[c], acc, 0, 0, 0);
  }

  float bcv = bc[colj];
  float lg[16], mx[16];
#pragma unroll
  for (int reg = 0; reg < 16; ++reg) {
    lg[reg] = acc[reg] + bcv;
    float v = lg[reg];
#pragma unroll
    for (int off = 16; off > 0; off >>= 1) v = fmaxf(v, __shfl_xor(v, off, 32));
    mx[reg] = v;
  }
  if ((lane & 31) == 0) {
#pragma unroll
    for (int reg = 0; reg < 16; ++reg) {
      int rl = rt * 32 + (reg & 3) + 8 * (reg >> 2) + 4 * (lane >> 5);
      red[0][ct][rl] = mx[reg];
    }
  }
  __syncthreads();

  float ex[16], sm[16];
#pragma unroll
  for (int reg = 0; reg < 16; ++reg) {
    int rl = rt * 32 + (reg & 3) + 8 * (reg >> 2) + 4 * (lane >> 5);
    float rmax = fmaxf(red[0][0][rl], red[0][1][rl]);
    ex[reg] = lg[reg] - rmax;
    float v = expf(ex[reg]);
#pragma unroll
    for (int off = 16; off > 0; off >>= 1) v += __shfl_xor(v, off, 32);
    sm[reg] = v;
  }
  if ((lane & 31) == 0) {
#pragma unroll
    for (int reg = 0; reg < 16; ++reg) {
      int rl = rt * 32 + (reg & 3) + 8 * (reg >> 2) + 4 * (lane >> 5);
      red[1][ct][rl] = sm[reg];
    }
  }
  __syncthreads();

#pragma unroll
  for (int reg = 0; reg < 16; ++reg) {
    int rl = rt * 32 + (reg & 3) + 8 * (reg >> 2) + 4 * (lane >> 5);
    int row = row0 + rl;
    if (row < N) {
      float total = red[1][0][rl] + red[1][1][rl];
      out[(size_t)row * 64 + colj] = ex[reg] - logf(total);
    }
  }
}

extern "C" void kernel_launch(void* const* d_in, const int* in_sizes, int n_in,
                              void* d_out, int out_size, void* d_ws, size_t ws_size,
                              hipStream_t stream) {
  const float* x   = (const float*)d_in[0];
  const int*   ei  = (const int*)d_in[1];
  const float* W1  = (const float*)d_in[2];
  const float* b1  = (const float*)d_in[3];
  const float* W2  = (const float*)d_in[4];
  const float* b2  = (const float*)d_in[5];
  const float* Wp1 = (const float*)d_in[6];
  const float* bp1 = (const float*)d_in[7];
  const float* Wp2 = (const float*)d_in[8];
  const float* bp2 = (const float*)d_in[9];
  float* out = (float*)d_out;

  int N = in_sizes[0] / 128;
  int E = in_sizes[1] / 2;
  const int* src = ei;
  const int* dst = ei + E;
  int nbins = (N + BIN_NODES - 1) >> BIN_SHIFT;

  // workspace layout (int granularity)
  float* dis   = (float*)d_ws;                    // N
  int*   deg   = (int*)(dis + N);                 // N
  int*   start = deg + N;                         // N
  int*   col   = start + N;                       // E
  int*   gcur  = col + ((E + 3) & ~3);            // 256 (zeroed by k_prep)
  us* Wt1h = (us*)(gcur + 256);                   // 16384 each
  us* Wt1l = Wt1h + 16384;
  us* Wt2h = Wt1l + 16384;
  us* Wt2l = Wt2h + 16384;
  us* Wch  = Wt2l + 16384;                        // 8192
  us* Wcl  = Wch + 8192;                          // 8192
  float* bc = (float*)(Wcl + 8192);               // 64 (+pad)
  uint2* binbuf = (uint2*)(bc + 80);              // nbins*CAPB uint2 (~19.3 MB)
  us* hbuf = (us*)(binbuf + (size_t)nbins * CAPB);  // (N+1)*128 bf16 (row N = zero, by k_prep)
  us* act  = hbuf + (size_t)(N + 1) * 128;          // N*128 bf16 = 25.6 MB

  // prep runs first: weight transform + gcur/zero-row init (no memset dispatches)
  k_prep<<<161, 256, 0, stream>>>(W1, W2, Wp1, Wp2, bp1, bp2,
                                  Wt1h, Wt1l, Wt2h, Wt2l, Wch, Wcl, bc,
                                  gcur, (int*)(hbuf + (size_t)N * 128));

  int ablocks = (E + EPB - 1) / EPB;
  k_binA<<<ablocks, 256, 0, stream>>>(src, dst, binbuf, gcur, E, nbins);
  k_passB<<<nbins, 256, 0, stream>>>(binbuf, gcur, deg, dis, start, col, N, nbins);

  int ntiles = (N + 31) / 32;
  int gemm_grid = ntiles < 1024 ? ntiles : 1024;
  int agblocks = (N + 7) / 8;
  int hblocks = (N + 63) / 64;

  // layer 1
  k_gemm1<<<gemm_grid, 256, 0, stream>>>(x, Wt1h, Wt1l, dis, hbuf, N, ntiles);
  k_gather<<<agblocks, 512, 0, stream>>>(hbuf, act, start, deg, col, dis, b1, N);
  // layer 2
  k_gemm2<<<gemm_grid, 256, 0, stream>>>(act, Wt2h, Wt2l, dis, hbuf, N, ntiles);
  k_gather<<<agblocks, 512, 0, stream>>>(hbuf, act, start, deg, col, dis, b2, N);
  // folded head (MFMA + fused log_softmax)
  k_head_mfma<<<hblocks, 256, 0, stream>>>(act, Wch, Wcl, bc, out, N);
}